// Round 12
// baseline (380.352 us; speedup 1.0000x reference)
//
#include <hip/hip_runtime.h>
#include <math.h>

#define NN 100000
#define EE 640000
#define GG 128
#define BN_EPS 1e-5f
#define NBLK 98  // ceil(NN/1024)

typedef __attribute__((ext_vector_type(8))) short short8;
typedef __attribute__((ext_vector_type(4))) float f32x4;

// ---------------- ws layout (byte offsets) ----------------
// Abf : [0,          25,600,000)   N x 128 bf16 (h0)
// Bbf : [25,600,000, 51,200,000)   N x 128 bf16 (h1)
// Z   : [51,200,000, 51,600,000)   N fp32
// SM  : [51,600,000, +16,448)      S0r(8x256) S1r(8x256) S2r(16)
// offs: [51,620,000, +400,004)     N+1 int
// bsum: [52,020,004, +512)
// csr : [52,020,516, +2,560,000)
// Wt  : [54,580,544, +163,840)     5 x 128x128 bf16 (transposed weights)
// Xbf : [54,744,384, +25,600,000)  N x 128 bf16 (x pre-rounded)
// deg/pos alias Abf region during CSR build (Abf not yet live).

__device__ __forceinline__ short f2bf(float f) {
    unsigned u = __float_as_uint(f);
    u += 0x7fffu + ((u >> 16) & 1);
    return (short)(u >> 16);
}
__device__ __forceinline__ float bf2f(short s) {
    return __uint_as_float(((unsigned)(unsigned short)s) << 16);
}
// XOR-swizzled LDS addressing (16B chunks), padding-free & ~conflict-free
__device__ __forceinline__ int swz(int row, int chunk) {
    return row * 128 + ((chunk ^ (row & 15)) << 3);
}
__device__ __forceinline__ int swze(int row, int col) {
    return row * 128 + (((col >> 3) ^ (row & 15)) << 3) + (col & 7);
}

// setup: weights -> bf16 transposed; x -> bf16; zero deg + stats
__global__ void k_setup(const float* __restrict__ x,
                        const float* __restrict__ W0a, const float* __restrict__ W0b,
                        const float* __restrict__ W1a, const float* __restrict__ W1b,
                        const float* __restrict__ W2a, short* __restrict__ Wt,
                        short* __restrict__ Xbf, int* __restrict__ deg,
                        float* __restrict__ smf) {
    int idx = blockIdx.x * 256 + threadIdx.x;  // grid covers 1.6M
    if (idx < 81920) {
        int wi = idx >> 14, r = idx & 16383;
        const float* W = (wi == 0) ? W0a : (wi == 1) ? W0b : (wi == 2) ? W1a
                        : (wi == 3) ? W1b : W2a;
        int k = r >> 7, n = r & 127;
        Wt[wi * 16384 + n * 128 + k] = f2bf(W[k * 128 + n]);
    }
    if (idx < NN) deg[idx] = 0;
    if (idx < 4112) smf[idx] = 0.0f;
    if (idx < 1600000) {  // 12.8M floats / 8
        const float4* xr = (const float4*)x + (size_t)idx * 2;
        float4 v0 = xr[0], v1 = xr[1];
        short8 o;
        o[0] = f2bf(v0.x); o[1] = f2bf(v0.y); o[2] = f2bf(v0.z); o[3] = f2bf(v0.w);
        o[4] = f2bf(v1.x); o[5] = f2bf(v1.y); o[6] = f2bf(v1.z); o[7] = f2bf(v1.w);
        *(short8*)(Xbf + (size_t)idx * 8) = o;
    }
}

// ---------------- CSR build ----------------
__global__ void k_hist(const int* __restrict__ ei, int* __restrict__ deg) {
    int e = blockIdx.x * 256 + threadIdx.x;
    if (e < EE) atomicAdd(&deg[ei[EE + e]], 1);
}

__global__ __launch_bounds__(1024) void k_scan1(const int* __restrict__ deg,
                                                int* __restrict__ offs,
                                                int* __restrict__ bsums) {
    __shared__ int sm[1024];
    int t = threadIdx.x;
    int i = blockIdx.x * 1024 + t;
    int v = (i < NN) ? deg[i] : 0;
    sm[t] = v;
    __syncthreads();
    for (int off = 1; off < 1024; off <<= 1) {
        int add = (t >= off) ? sm[t - off] : 0;
        __syncthreads();
        sm[t] += add;
        __syncthreads();
    }
    if (i < NN) offs[i] = sm[t] - v;  // exclusive within block
    if (t == 1023) bsums[blockIdx.x] = sm[1023];
}

// scan3 with scan2 folded in: each block reduces bsums prefix itself
__global__ __launch_bounds__(1024) void k_scan3(int* __restrict__ offs,
                                                const int* __restrict__ bsums,
                                                int* __restrict__ pos) {
    __shared__ int smb[128];
    __shared__ int baseS;
    int t = threadIdx.x;
    if (t < 128) smb[t] = (t < NBLK) ? bsums[t] : 0;
    __syncthreads();
    if (t == 0) {
        int b = 0;
        for (int i = 0; i < (int)blockIdx.x; ++i) b += smb[i];
        baseS = b;
    }
    __syncthreads();
    int i = blockIdx.x * 1024 + t;
    if (i < NN) {
        int o = offs[i] + baseS;
        offs[i] = o;
        pos[i] = o;
    }
    if (i == 0) offs[NN] = EE;
}

__global__ void k_fill(const int* __restrict__ ei, int* __restrict__ pos,
                       int* __restrict__ csr) {
    int e = blockIdx.x * 256 + threadIdx.x;
    if (e < EE) {
        int d = ei[EE + e];
        int p = atomicAdd(&pos[d], 1);
        csr[p] = ei[e];
    }
}

// ---------------- fused gather + GIN MLP, bf16 MFMA, 128x128 tile ----------------
// 512 threads (8 waves), 2 blocks/CU. Gather: 8 lanes/node x 2 chunks/lane,
// 2 rows/thread, 4-way edge unroll -> 8 loads in flight per thread.
// wave w: rh = w&3 (rows rh*32..+32), ch = w>>2 (cols ch*64..+64); acc[2][4].
// MODE 0: input Xbf (no BN), full MLP -> hout + BN stats (8-replica)
// MODE 1: input bf16 h, BN+ReLU on gathered rows, full MLP -> hout + stats
// MODE 2: input bf16 h, BN+ReLU, gemm1 -> fused dot w2 -> z + (s,ss) replicas
template <int MODE>
__global__ __launch_bounds__(512, 4) void k_gmlp(const short* __restrict__ hin,
                                                 const int* __restrict__ offs,
                                                 const int* __restrict__ csr,
                                                 const float* __restrict__ rep,
                                                 const float* __restrict__ g,
                                                 const float* __restrict__ be,
                                                 const short* __restrict__ Wta,
                                                 const float* __restrict__ ba,
                                                 const short* __restrict__ Wtb,
                                                 const float* __restrict__ bb,
                                                 short* __restrict__ hout,
                                                 float* __restrict__ statsRep,
                                                 const float* __restrict__ w2,
                                                 const float* __restrict__ b2,
                                                 float* __restrict__ z,
                                                 float* __restrict__ s2rep) {
    __shared__ short Asb[16384];   // 128x128 bf16, swizzled
    __shared__ short Wsb[16384];   // 128x128 bf16 weight tile
    __shared__ float parS[128], parH[128];
    __shared__ float redS[1024];
    const int t = threadIdx.x;
    const int row0 = blockIdx.x * 128;
    const int lane = t & 63, wave = t >> 6;
    const int r16 = lane & 15, q = lane >> 4;
    const int rh = wave & 3, ch = wave >> 2;
    const int RA = rh * 32, CB = ch * 64;
    const int l = t & 15;

    // ---- BN params (MODE != 0) ----
    if constexpr (MODE != 0) {
        if (t < 128) {
            float s = 0.f, ss = 0.f;
#pragma unroll
            for (int r = 0; r < 8; ++r) {
                s += rep[r * 256 + t];
                ss += rep[r * 256 + 128 + t];
            }
            const float inv = 1.0f / (float)NN;
            float mu = s * inv;
            float var = ss * inv - mu * mu;
            float sc = g[t] / sqrtf(var + BN_EPS);
            parS[t] = sc;
            parH[t] = be[t] - mu * sc;
        }
        __syncthreads();
    }

    // ---- stage Wa^T; prefetch Wb^T into regs (MODE != 2) ----
    short8 wpre[4];
#pragma unroll
    for (int i = 0; i < 4; ++i) {
        int f = i * 512 + t;
        int r = f >> 4, c8 = f & 15;
        *(short8*)&Wsb[swz(r, c8)] = *(const short8*)(Wta + r * 128 + c8 * 8);
        if constexpr (MODE != 2) wpre[i] = *(const short8*)(Wtb + r * 128 + c8 * 8);
    }

    // ---- fused gather: 8 lanes/node, 2 chunks/lane, 2 rows/thread ----
    const int lane8 = t & 7;       // chunk pair: c0 = lane8*2, c1 = lane8*2+1
    const int rw = t >> 3;         // row slot 0..63
    const int co = lane8 * 16;     // element offset of this thread's 16 elems
    float sc16[16], sh16[16];
    if constexpr (MODE != 0) {
#pragma unroll
        for (int j = 0; j < 16; ++j) { sc16[j] = parS[co + j]; sh16[j] = parH[co + j]; }
    }
#pragma unroll
    for (int p = 0; p < 2; ++p) {
        int r = p * 64 + rw;
        int gr = row0 + r;
        float f16[16];
#pragma unroll
        for (int k = 0; k < 16; ++k) f16[k] = 0.f;
        if (gr < NN) {
            int j0 = offs[gr], j1 = offs[gr + 1];
            const short* rowp = hin + (size_t)gr * 128 + co;
            short8 v0 = *(const short8*)rowp;
            short8 v1 = *(const short8*)(rowp + 8);
#pragma unroll
            for (int k = 0; k < 8; ++k) {
                if constexpr (MODE != 0) {
                    f16[k] = fmaxf(fmaf(bf2f(v0[k]), sc16[k], sh16[k]), 0.f);
                    f16[8 + k] = fmaxf(fmaf(bf2f(v1[k]), sc16[8 + k], sh16[8 + k]), 0.f);
                } else {
                    f16[k] = bf2f(v0[k]);
                    f16[8 + k] = bf2f(v1[k]);
                }
            }
            int j = j0;
            for (; j + 3 < j1; j += 4) {
                int s0 = csr[j], s1 = csr[j + 1], s2 = csr[j + 2], s3 = csr[j + 3];
                const short* p0 = hin + (size_t)s0 * 128 + co;
                const short* p1 = hin + (size_t)s1 * 128 + co;
                const short* p2 = hin + (size_t)s2 * 128 + co;
                const short* p3 = hin + (size_t)s3 * 128 + co;
                short8 a0 = *(const short8*)p0, b0 = *(const short8*)(p0 + 8);
                short8 a1 = *(const short8*)p1, b1 = *(const short8*)(p1 + 8);
                short8 a2 = *(const short8*)p2, b2v = *(const short8*)(p2 + 8);
                short8 a3 = *(const short8*)p3, b3 = *(const short8*)(p3 + 8);
#pragma unroll
                for (int k = 0; k < 8; ++k) {
                    if constexpr (MODE != 0) {
                        f16[k] += fmaxf(fmaf(bf2f(a0[k]), sc16[k], sh16[k]), 0.f)
                                + fmaxf(fmaf(bf2f(a1[k]), sc16[k], sh16[k]), 0.f)
                                + fmaxf(fmaf(bf2f(a2[k]), sc16[k], sh16[k]), 0.f)
                                + fmaxf(fmaf(bf2f(a3[k]), sc16[k], sh16[k]), 0.f);
                        f16[8 + k] += fmaxf(fmaf(bf2f(b0[k]), sc16[8 + k], sh16[8 + k]), 0.f)
                                    + fmaxf(fmaf(bf2f(b1[k]), sc16[8 + k], sh16[8 + k]), 0.f)
                                    + fmaxf(fmaf(bf2f(b2v[k]), sc16[8 + k], sh16[8 + k]), 0.f)
                                    + fmaxf(fmaf(bf2f(b3[k]), sc16[8 + k], sh16[8 + k]), 0.f);
                    } else {
                        f16[k] += bf2f(a0[k]) + bf2f(a1[k]) + bf2f(a2[k]) + bf2f(a3[k]);
                        f16[8 + k] += bf2f(b0[k]) + bf2f(b1[k]) + bf2f(b2v[k]) + bf2f(b3[k]);
                    }
                }
            }
            for (; j < j1; ++j) {
                int s0 = csr[j];
                const short* p0 = hin + (size_t)s0 * 128 + co;
                short8 a0 = *(const short8*)p0, b0 = *(const short8*)(p0 + 8);
#pragma unroll
                for (int k = 0; k < 8; ++k) {
                    if constexpr (MODE != 0) {
                        f16[k] += fmaxf(fmaf(bf2f(a0[k]), sc16[k], sh16[k]), 0.f);
                        f16[8 + k] += fmaxf(fmaf(bf2f(b0[k]), sc16[8 + k], sh16[8 + k]), 0.f);
                    } else {
                        f16[k] += bf2f(a0[k]);
                        f16[8 + k] += bf2f(b0[k]);
                    }
                }
            }
        }
        short8 o0, o1;
#pragma unroll
        for (int k = 0; k < 8; ++k) { o0[k] = f2bf(f16[k]); o1[k] = f2bf(f16[8 + k]); }
        *(short8*)&Asb[swz(r, lane8 * 2)] = o0;
        *(short8*)&Asb[swz(r, lane8 * 2 + 1)] = o1;
    }
    __syncthreads();

    // ---- gemm1 ----
    f32x4 acc[2][4];
#pragma unroll
    for (int rt = 0; rt < 2; ++rt)
#pragma unroll
        for (int ct = 0; ct < 4; ++ct) acc[rt][ct] = (f32x4)0.f;
#pragma unroll
    for (int kk = 0; kk < 4; ++kk) {
        short8 b[4], a[2];
#pragma unroll
        for (int ct = 0; ct < 4; ++ct)
            b[ct] = *(const short8*)&Wsb[swz(CB + ct * 16 + r16, kk * 4 + q)];
#pragma unroll
        for (int rt = 0; rt < 2; ++rt)
            a[rt] = *(const short8*)&Asb[swz(RA + rt * 16 + r16, kk * 4 + q)];
#pragma unroll
        for (int rt = 0; rt < 2; ++rt)
#pragma unroll
            for (int ct = 0; ct < 4; ++ct)
                acc[rt][ct] = __builtin_amdgcn_mfma_f32_16x16x32_bf16(a[rt], b[ct], acc[rt][ct], 0, 0, 0);
    }
    __syncthreads();  // gemm1 LDS reads done

    // mid = relu(acc + ba) -> Asb; (MODE != 2): wpre -> Wsb
    float bav[4];
#pragma unroll
    for (int ct = 0; ct < 4; ++ct) bav[ct] = ba[CB + ct * 16 + r16];
#pragma unroll
    for (int rt = 0; rt < 2; ++rt)
#pragma unroll
        for (int ct = 0; ct < 4; ++ct)
#pragma unroll
            for (int rg = 0; rg < 4; ++rg) {
                float m = fmaxf(acc[rt][ct][rg] + bav[ct], 0.f);
                Asb[swze(RA + rt * 16 + q * 4 + rg, CB + ct * 16 + r16)] = f2bf(m);
            }
    if constexpr (MODE != 2) {
#pragma unroll
        for (int i = 0; i < 4; ++i) {
            int f = i * 512 + t;
            int r = f >> 4, c8 = f & 15;
            *(short8*)&Wsb[swz(r, c8)] = wpre[i];
        }
    }
    __syncthreads();

    if constexpr (MODE == 2) {
        // fused final linear: z = mid . w2 + b2, plus (s,ss)
        const int rr = t >> 4;
        float4 w0 = ((const float4*)w2)[l * 2];
        float4 w1 = ((const float4*)w2)[l * 2 + 1];
        float b2v = b2[0];
        float s = 0.f, ss = 0.f;
#pragma unroll
        for (int p = 0; p < 4; ++p) {
            int r = p * 32 + rr;
            int gr = row0 + r;
            short8 v = *(const short8*)&Asb[swz(r, l)];
            float pp = bf2f(v[0]) * w0.x + bf2f(v[1]) * w0.y + bf2f(v[2]) * w0.z +
                       bf2f(v[3]) * w0.w + bf2f(v[4]) * w1.x + bf2f(v[5]) * w1.y +
                       bf2f(v[6]) * w1.z + bf2f(v[7]) * w1.w;
#pragma unroll
            for (int off = 1; off < 16; off <<= 1) pp += __shfl_xor(pp, off, 16);
            if (l == 0 && gr < NN) {
                float h2 = pp + b2v;
                z[gr] = h2;
                s += h2;
                ss += h2 * h2;
            }
        }
        s += __shfl_xor(s, 16); s += __shfl_xor(s, 32);
        ss += __shfl_xor(ss, 16); ss += __shfl_xor(ss, 32);
        if ((t & 63) == 0) { redS[wave * 2] = s; redS[wave * 2 + 1] = ss; }
        __syncthreads();
        if (t == 0) {
            float S = 0.f, SS = 0.f;
#pragma unroll
            for (int w = 0; w < 8; ++w) { S += redS[w * 2]; SS += redS[w * 2 + 1]; }
            int rp = (blockIdx.x & 7) * 2;
            unsafeAtomicAdd(&s2rep[rp], S);
            unsafeAtomicAdd(&s2rep[rp + 1], SS);
        }
        return;
    } else {
        // ---- gemm2 ----
#pragma unroll
        for (int rt = 0; rt < 2; ++rt)
#pragma unroll
            for (int ct = 0; ct < 4; ++ct) acc[rt][ct] = (f32x4)0.f;
#pragma unroll
        for (int kk = 0; kk < 4; ++kk) {
            short8 b[4], a[2];
#pragma unroll
            for (int ct = 0; ct < 4; ++ct)
                b[ct] = *(const short8*)&Wsb[swz(CB + ct * 16 + r16, kk * 4 + q)];
#pragma unroll
            for (int rt = 0; rt < 2; ++rt)
                a[rt] = *(const short8*)&Asb[swz(RA + rt * 16 + r16, kk * 4 + q)];
#pragma unroll
            for (int rt = 0; rt < 2; ++rt)
#pragma unroll
                for (int ct = 0; ct < 4; ++ct)
                    acc[rt][ct] = __builtin_amdgcn_mfma_f32_16x16x32_bf16(a[rt], b[ct], acc[rt][ct], 0, 0, 0);
        }
        __syncthreads();  // gemm2 LDS reads done

        float bbv[4];
#pragma unroll
        for (int ct = 0; ct < 4; ++ct) bbv[ct] = bb[CB + ct * 16 + r16];
        float s[4] = {0.f, 0.f, 0.f, 0.f}, ss[4] = {0.f, 0.f, 0.f, 0.f};
#pragma unroll
        for (int rt = 0; rt < 2; ++rt)
#pragma unroll
            for (int ct = 0; ct < 4; ++ct)
#pragma unroll
                for (int rg = 0; rg < 4; ++rg) {
                    int lr = RA + rt * 16 + q * 4 + rg;
                    int gr = row0 + lr;
                    float hv = acc[rt][ct][rg] + bbv[ct];
                    if (gr < NN) { s[ct] += hv; ss[ct] += hv * hv; }
                    Asb[swze(lr, CB + ct * 16 + r16)] = f2bf(hv);
                }
#pragma unroll
        for (int ct = 0; ct < 4; ++ct) {
            s[ct] += __shfl_xor(s[ct], 16);
            s[ct] += __shfl_xor(s[ct], 32);
            ss[ct] += __shfl_xor(ss[ct], 16);
            ss[ct] += __shfl_xor(ss[ct], 32);
        }
        if (lane < 16) {
#pragma unroll
            for (int ct = 0; ct < 4; ++ct) {
                int col = CB + ct * 16 + r16;
                redS[rh * 256 + col] = s[ct];
                redS[rh * 256 + 128 + col] = ss[ct];
            }
        }
        __syncthreads();
        if (t < 256) {
            float v = redS[t] + redS[256 + t] + redS[512 + t] + redS[768 + t];
            unsafeAtomicAdd(&statsRep[(blockIdx.x & 7) * 256 + t], v);
        }
        // coalesced bf16 store of h tile
#pragma unroll
        for (int i = 0; i < 4; ++i) {
            int f = i * 512 + t;
            int r = f >> 4, c8 = f & 15;
            int gr = row0 + r;
            if (gr < NN)
                *(short8*)(hout + (size_t)gr * 128 + c8 * 8) = *(const short8*)&Asb[swz(r, c8)];
        }
    }
}

__device__ __forceinline__ int lbound(const int* __restrict__ b, int val) {
    int lo = 0, hi = NN;
    while (lo < hi) {
        int m = (lo + hi) >> 1;
        if (b[m] < val) lo = m + 1; else hi = m;
    }
    return lo;
}

// fused BN(1) + segment softmax(temp 5): one block per graph (batch sorted)
__global__ void k_softmax(const float* __restrict__ zr, const float* __restrict__ s2rep,
                          const float* __restrict__ g2, const float* __restrict__ be2,
                          const int* __restrict__ batch, float* __restrict__ out) {
    __shared__ float rb[4];
    const int g = blockIdx.x, t = threadIdx.x;
    const int lo = lbound(batch, g), hi = lbound(batch, g + 1);
    float s = 0.f, ssq = 0.f;
#pragma unroll
    for (int i = 0; i < 8; ++i) { s += s2rep[i * 2]; ssq += s2rep[i * 2 + 1]; }
    const float mu = s / (float)NN;
    const float var = ssq / (float)NN - mu * mu;
    const float sc = g2[0] / sqrtf(var + BN_EPS) * 0.2f;
    const float sh = (be2[0] - mu * g2[0] / sqrtf(var + BN_EPS)) * 0.2f;

    float m = -INFINITY;
    for (int i = lo + t; i < hi; i += 256) m = fmaxf(m, fmaf(zr[i], sc, sh));
#pragma unroll
    for (int off = 1; off < 64; off <<= 1) m = fmaxf(m, __shfl_xor(m, off, 64));
    if ((t & 63) == 0) rb[t >> 6] = m;
    __syncthreads();
    float gmax = fmaxf(fmaxf(rb[0], rb[1]), fmaxf(rb[2], rb[3]));
    __syncthreads();

    float sum = 0.f;
    for (int i = lo + t; i < hi; i += 256) {
        float e = expf(fmaf(zr[i], sc, sh) - gmax);
        out[i] = e;
        sum += e;
    }
#pragma unroll
    for (int off = 1; off < 64; off <<= 1) sum += __shfl_xor(sum, off, 64);
    if ((t & 63) == 0) rb[t >> 6] = sum;
    __syncthreads();
    float S = rb[0] + rb[1] + rb[2] + rb[3];
    float inv = 1.0f / (S + 1e-16f);
    for (int i = lo + t; i < hi; i += 256) out[i] *= inv;
}

extern "C" void kernel_launch(void* const* d_in, const int* in_sizes, int n_in,
                              void* d_out, int out_size, void* d_ws, size_t ws_size,
                              hipStream_t stream) {
    const float* x   = (const float*)d_in[0];
    const int* ei    = (const int*)d_in[1];
    const int* batch = (const int*)d_in[2];
    const float *W0a = (const float*)d_in[3],  *b0a = (const float*)d_in[4];
    const float *W0b = (const float*)d_in[5],  *b0b = (const float*)d_in[6];
    const float *g0  = (const float*)d_in[7],  *be0 = (const float*)d_in[8];
    const float *W1a = (const float*)d_in[9],  *b1a = (const float*)d_in[10];
    const float *W1b = (const float*)d_in[11], *b1b = (const float*)d_in[12];
    const float *g1  = (const float*)d_in[13], *be1 = (const float*)d_in[14];
    const float *W2a = (const float*)d_in[15], *b2a = (const float*)d_in[16];
    const float *W2b = (const float*)d_in[17], *b2b = (const float*)d_in[18];
    const float *g2  = (const float*)d_in[19], *be2 = (const float*)d_in[20];
    float* out = (float*)d_out;

    char* wsb = (char*)d_ws;
    short* Abf = (short*)wsb;
    short* Bbf = (short*)(wsb + 25600000);
    float* Zb  = (float*)(wsb + 51200000);
    float* SMf = (float*)(wsb + 51600000);
    float* S0r = SMf;               // 8 x 256
    float* S1r = SMf + 2048;        // 8 x 256
    float* S2r = SMf + 4096;        // 8 x 2
    int* offs  = (int*)(wsb + 51620000);
    int* bsums = (int*)(wsb + 52020004);
    int* csr   = (int*)(wsb + 52020516);
    short* Wt  = (short*)(wsb + 54580544);
    short* Xbf = (short*)(wsb + 54744384);
    // deg/pos alias Abf during CSR build
    int* deg = (int*)wsb;
    int* pos = (int*)(wsb + 400000);

    const int gE    = (EE + 255) / 256;     // 2500
    const int gGmlp = (NN + 127) / 128;     // 782

    k_setup<<<6250, 256, 0, stream>>>(x, W0a, W0b, W1a, W1b, W2a, Wt, Xbf, deg, SMf);

    // ---- CSR build (reused all 3 layers) ----
    k_hist<<<gE, 256, 0, stream>>>(ei, deg);
    k_scan1<<<NBLK, 1024, 0, stream>>>(deg, offs, bsums);
    k_scan3<<<NBLK, 1024, 0, stream>>>(offs, bsums, pos);
    k_fill<<<gE, 256, 0, stream>>>(ei, pos, csr);

    // layer 0: fused gather(Xbf) + MLP -> Abf + stats
    k_gmlp<0><<<gGmlp, 512, 0, stream>>>(Xbf, offs, csr, nullptr, nullptr, nullptr,
                                         Wt, b0a, Wt + 16384, b0b, Abf, S0r,
                                         nullptr, nullptr, nullptr, nullptr);
    // layer 1: fused gather(Abf, BN0+ReLU) + MLP -> Bbf + stats
    k_gmlp<1><<<gGmlp, 512, 0, stream>>>(Abf, offs, csr, S0r, g0, be0,
                                         Wt + 2 * 16384, b1a, Wt + 3 * 16384, b1b, Bbf, S1r,
                                         nullptr, nullptr, nullptr, nullptr);
    // layer 2: fused gather(Bbf, BN1+ReLU) + gemm1 + final dot -> Zb + s2
    k_gmlp<2><<<gGmlp, 512, 0, stream>>>(Bbf, offs, csr, S1r, g1, be1,
                                         Wt + 4 * 16384, b2a, nullptr, nullptr,
                                         nullptr, nullptr, W2b, b2b, Zb, S2r);

    // fused BN(1) + segment softmax (temperature 5)
    k_softmax<<<GG, 256, 0, stream>>>(Zb, S2r, g2, be2, batch, out);
}

// Round 13
// 372.185 us; speedup vs baseline: 1.0219x; 1.0219x over previous
//
#include <hip/hip_runtime.h>
#include <math.h>

#define NN 100000
#define EE 640000
#define GG 128
#define BN_EPS 1e-5f
#define NBLK 98  // ceil(NN/1024)

typedef __attribute__((ext_vector_type(8))) short short8;
typedef __attribute__((ext_vector_type(4))) float f32x4;

// ---------------- ws layout (byte offsets) ----------------
// Abf : [0,          25,600,000)   N x 128 bf16 (h0)
// Bbf : [25,600,000, 51,200,000)   N x 128 bf16 (h1)
// Z   : [51,200,000, 51,600,000)   N fp32
// SM  : [51,600,000, +16,448)      S0r(8x256) S1r(8x256) S2r(16)
// offs: [51,620,000, +400,004)     N+1 int
// bsum: [52,020,004, +512)
// csr : [52,020,516, +2,560,000)
// Wt  : [54,580,544, +163,840)     5 x 128x128 bf16 (transposed weights)
// Xbf : [54,744,384, +25,600,000)  N x 128 bf16 (x pre-rounded)
// deg/pos alias Abf region during CSR build (Abf not yet live).

__device__ __forceinline__ short f2bf(float f) {
    unsigned u = __float_as_uint(f);
    u += 0x7fffu + ((u >> 16) & 1);
    return (short)(u >> 16);
}
__device__ __forceinline__ float bf2f(short s) {
    return __uint_as_float(((unsigned)(unsigned short)s) << 16);
}
// XOR-swizzled LDS addressing (16B chunks), padding-free & ~conflict-free
__device__ __forceinline__ int swz(int row, int chunk) {
    return row * 128 + ((chunk ^ (row & 15)) << 3);
}
__device__ __forceinline__ int swze(int row, int col) {
    return row * 128 + (((col >> 3) ^ (row & 15)) << 3) + (col & 7);
}

// setup: weights -> bf16 transposed; x -> bf16; zero deg + stats
__global__ void k_setup(const float* __restrict__ x,
                        const float* __restrict__ W0a, const float* __restrict__ W0b,
                        const float* __restrict__ W1a, const float* __restrict__ W1b,
                        const float* __restrict__ W2a, short* __restrict__ Wt,
                        short* __restrict__ Xbf, int* __restrict__ deg,
                        float* __restrict__ smf) {
    int idx = blockIdx.x * 256 + threadIdx.x;  // grid covers 1.6M
    if (idx < 81920) {
        int wi = idx >> 14, r = idx & 16383;
        const float* W = (wi == 0) ? W0a : (wi == 1) ? W0b : (wi == 2) ? W1a
                        : (wi == 3) ? W1b : W2a;
        int k = r >> 7, n = r & 127;
        Wt[wi * 16384 + n * 128 + k] = f2bf(W[k * 128 + n]);
    }
    if (idx < NN) deg[idx] = 0;
    if (idx < 4112) smf[idx] = 0.0f;
    if (idx < 1600000) {  // 12.8M floats / 8
        const float4* xr = (const float4*)x + (size_t)idx * 2;
        float4 v0 = xr[0], v1 = xr[1];
        short8 o;
        o[0] = f2bf(v0.x); o[1] = f2bf(v0.y); o[2] = f2bf(v0.z); o[3] = f2bf(v0.w);
        o[4] = f2bf(v1.x); o[5] = f2bf(v1.y); o[6] = f2bf(v1.z); o[7] = f2bf(v1.w);
        *(short8*)(Xbf + (size_t)idx * 8) = o;
    }
}

// ---------------- CSR build ----------------
__global__ void k_hist(const int* __restrict__ ei, int* __restrict__ deg) {
    int e = blockIdx.x * 256 + threadIdx.x;
    if (e < EE) atomicAdd(&deg[ei[EE + e]], 1);
}

__global__ __launch_bounds__(1024) void k_scan1(const int* __restrict__ deg,
                                                int* __restrict__ offs,
                                                int* __restrict__ bsums) {
    __shared__ int sm[1024];
    int t = threadIdx.x;
    int i = blockIdx.x * 1024 + t;
    int v = (i < NN) ? deg[i] : 0;
    sm[t] = v;
    __syncthreads();
    for (int off = 1; off < 1024; off <<= 1) {
        int add = (t >= off) ? sm[t - off] : 0;
        __syncthreads();
        sm[t] += add;
        __syncthreads();
    }
    if (i < NN) offs[i] = sm[t] - v;  // exclusive within block
    if (t == 1023) bsums[blockIdx.x] = sm[1023];
}

// scan3 with scan2 folded in: each block reduces bsums prefix itself
__global__ __launch_bounds__(1024) void k_scan3(int* __restrict__ offs,
                                                const int* __restrict__ bsums,
                                                int* __restrict__ pos) {
    __shared__ int smb[128];
    __shared__ int baseS;
    int t = threadIdx.x;
    if (t < 128) smb[t] = (t < NBLK) ? bsums[t] : 0;
    __syncthreads();
    if (t == 0) {
        int b = 0;
        for (int i = 0; i < (int)blockIdx.x; ++i) b += smb[i];
        baseS = b;
    }
    __syncthreads();
    int i = blockIdx.x * 1024 + t;
    if (i < NN) {
        int o = offs[i] + baseS;
        offs[i] = o;
        pos[i] = o;
    }
    if (i == 0) offs[NN] = EE;
}

__global__ void k_fill(const int* __restrict__ ei, int* __restrict__ pos,
                       int* __restrict__ csr) {
    int e = blockIdx.x * 256 + threadIdx.x;
    if (e < EE) {
        int d = ei[EE + e];
        int p = atomicAdd(&pos[d], 1);
        csr[p] = ei[e];
    }
}

// ---------------- fused gather + GIN MLP, bf16 MFMA, 128x128 tile ----------------
// 512 threads (8 waves), 2 blocks/CU (16 waves/CU for the gather phase).
// Gather: 16 lanes/node, 4 nodes/thread, 4-way edge unroll (R11-verified layout:
// one coalesced 256-B segment per source row, 4 rows in flight/wave, 0 conflicts).
// wave w: rh = w&3 (rows rh*32..+32), ch = w>>2 (cols ch*64..+64); acc[2][4].
// MODE 0: input Xbf (no BN), full MLP -> hout + BN stats (8-replica)
// MODE 1: input bf16 h, BN+ReLU on gathered rows, full MLP -> hout + stats
// MODE 2: input bf16 h, BN+ReLU, gemm1 -> fused dot w2 -> z + (s,ss) replicas
template <int MODE>
__global__ __launch_bounds__(512, 4) void k_gmlp(const short* __restrict__ hin,
                                                 const int* __restrict__ offs,
                                                 const int* __restrict__ csr,
                                                 const float* __restrict__ rep,
                                                 const float* __restrict__ g,
                                                 const float* __restrict__ be,
                                                 const short* __restrict__ Wta,
                                                 const float* __restrict__ ba,
                                                 const short* __restrict__ Wtb,
                                                 const float* __restrict__ bb,
                                                 short* __restrict__ hout,
                                                 float* __restrict__ statsRep,
                                                 const float* __restrict__ w2,
                                                 const float* __restrict__ b2,
                                                 float* __restrict__ z,
                                                 float* __restrict__ s2rep) {
    __shared__ short Asb[16384];   // 128x128 bf16, swizzled
    __shared__ short Wsb[16384];   // 128x128 bf16 weight tile
    __shared__ float parS[128], parH[128];
    __shared__ float redS[1024];
    const int t = threadIdx.x;
    const int row0 = blockIdx.x * 128;
    const int lane = t & 63, wave = t >> 6;
    const int r16 = lane & 15, q = lane >> 4;
    const int rh = wave & 3, ch = wave >> 2;
    const int RA = rh * 32, CB = ch * 64;
    const int l = t & 15;

    // ---- BN params (MODE != 0) ----
    if constexpr (MODE != 0) {
        if (t < 128) {
            float s = 0.f, ss = 0.f;
#pragma unroll
            for (int r = 0; r < 8; ++r) {
                s += rep[r * 256 + t];
                ss += rep[r * 256 + 128 + t];
            }
            const float inv = 1.0f / (float)NN;
            float mu = s * inv;
            float var = ss * inv - mu * mu;
            float sc = g[t] / sqrtf(var + BN_EPS);
            parS[t] = sc;
            parH[t] = be[t] - mu * sc;
        }
        __syncthreads();
    }

    // ---- stage Wa^T; prefetch Wb^T into regs (MODE != 2) ----
    short8 wpre[4];
#pragma unroll
    for (int i = 0; i < 4; ++i) {
        int f = i * 512 + t;
        int r = f >> 4, c8 = f & 15;
        *(short8*)&Wsb[swz(r, c8)] = *(const short8*)(Wta + r * 128 + c8 * 8);
        if constexpr (MODE != 2) wpre[i] = *(const short8*)(Wtb + r * 128 + c8 * 8);
    }

    // ---- fused gather: 4 nodes/thread, 16 lanes/node, 4-way edge unroll ----
    float sc8[8], sh8[8];
    if constexpr (MODE != 0) {
#pragma unroll
        for (int j = 0; j < 8; ++j) { sc8[j] = parS[l * 8 + j]; sh8[j] = parH[l * 8 + j]; }
    }
#pragma unroll
    for (int p = 0; p < 4; ++p) {
        int r = p * 32 + (t >> 4);
        int gr = row0 + r;
        float f8[8] = {0.f, 0.f, 0.f, 0.f, 0.f, 0.f, 0.f, 0.f};
        if (gr < NN) {
            int j0 = offs[gr], j1 = offs[gr + 1];
            short8 v = *(const short8*)(hin + (size_t)gr * 128 + l * 8);
#pragma unroll
            for (int k = 0; k < 8; ++k)
                f8[k] = (MODE != 0) ? fmaxf(fmaf(bf2f(v[k]), sc8[k], sh8[k]), 0.f) : bf2f(v[k]);
            int j = j0;
            for (; j + 3 < j1; j += 4) {
                int s0 = csr[j], s1 = csr[j + 1], s2 = csr[j + 2], s3 = csr[j + 3];
                short8 w0 = *(const short8*)(hin + (size_t)s0 * 128 + l * 8);
                short8 w1 = *(const short8*)(hin + (size_t)s1 * 128 + l * 8);
                short8 w2v = *(const short8*)(hin + (size_t)s2 * 128 + l * 8);
                short8 w3 = *(const short8*)(hin + (size_t)s3 * 128 + l * 8);
#pragma unroll
                for (int k = 0; k < 8; ++k) {
                    if constexpr (MODE != 0) {
                        f8[k] += fmaxf(fmaf(bf2f(w0[k]), sc8[k], sh8[k]), 0.f)
                               + fmaxf(fmaf(bf2f(w1[k]), sc8[k], sh8[k]), 0.f)
                               + fmaxf(fmaf(bf2f(w2v[k]), sc8[k], sh8[k]), 0.f)
                               + fmaxf(fmaf(bf2f(w3[k]), sc8[k], sh8[k]), 0.f);
                    } else {
                        f8[k] += bf2f(w0[k]) + bf2f(w1[k]) + bf2f(w2v[k]) + bf2f(w3[k]);
                    }
                }
            }
            for (; j < j1; ++j) {
                int s0 = csr[j];
                short8 w0 = *(const short8*)(hin + (size_t)s0 * 128 + l * 8);
#pragma unroll
                for (int k = 0; k < 8; ++k)
                    f8[k] += (MODE != 0) ? fmaxf(fmaf(bf2f(w0[k]), sc8[k], sh8[k]), 0.f)
                                         : bf2f(w0[k]);
            }
        }
        short8 o;
#pragma unroll
        for (int k = 0; k < 8; ++k) o[k] = f2bf(f8[k]);
        *(short8*)&Asb[swz(r, l)] = o;
    }
    __syncthreads();

    // ---- gemm1 ----
    f32x4 acc[2][4];
#pragma unroll
    for (int rt = 0; rt < 2; ++rt)
#pragma unroll
        for (int ct = 0; ct < 4; ++ct) acc[rt][ct] = (f32x4)0.f;
#pragma unroll
    for (int kk = 0; kk < 4; ++kk) {
        short8 b[4], a[2];
#pragma unroll
        for (int ct = 0; ct < 4; ++ct)
            b[ct] = *(const short8*)&Wsb[swz(CB + ct * 16 + r16, kk * 4 + q)];
#pragma unroll
        for (int rt = 0; rt < 2; ++rt)
            a[rt] = *(const short8*)&Asb[swz(RA + rt * 16 + r16, kk * 4 + q)];
#pragma unroll
        for (int rt = 0; rt < 2; ++rt)
#pragma unroll
            for (int ct = 0; ct < 4; ++ct)
                acc[rt][ct] = __builtin_amdgcn_mfma_f32_16x16x32_bf16(a[rt], b[ct], acc[rt][ct], 0, 0, 0);
    }
    __syncthreads();  // gemm1 LDS reads done

    // mid = relu(acc + ba) -> Asb; (MODE != 2): wpre -> Wsb
    float bav[4];
#pragma unroll
    for (int ct = 0; ct < 4; ++ct) bav[ct] = ba[CB + ct * 16 + r16];
#pragma unroll
    for (int rt = 0; rt < 2; ++rt)
#pragma unroll
        for (int ct = 0; ct < 4; ++ct)
#pragma unroll
            for (int rg = 0; rg < 4; ++rg) {
                float m = fmaxf(acc[rt][ct][rg] + bav[ct], 0.f);
                Asb[swze(RA + rt * 16 + q * 4 + rg, CB + ct * 16 + r16)] = f2bf(m);
            }
    if constexpr (MODE != 2) {
#pragma unroll
        for (int i = 0; i < 4; ++i) {
            int f = i * 512 + t;
            int r = f >> 4, c8 = f & 15;
            *(short8*)&Wsb[swz(r, c8)] = wpre[i];
        }
    }
    __syncthreads();

    if constexpr (MODE == 2) {
        // fused final linear: z = mid . w2 + b2, plus (s,ss)
        const int rr = t >> 4;
        float4 w0 = ((const float4*)w2)[l * 2];
        float4 w1 = ((const float4*)w2)[l * 2 + 1];
        float b2v = b2[0];
        float s = 0.f, ss = 0.f;
#pragma unroll
        for (int p = 0; p < 4; ++p) {
            int r = p * 32 + rr;
            int gr = row0 + r;
            short8 v = *(const short8*)&Asb[swz(r, l)];
            float pp = bf2f(v[0]) * w0.x + bf2f(v[1]) * w0.y + bf2f(v[2]) * w0.z +
                       bf2f(v[3]) * w0.w + bf2f(v[4]) * w1.x + bf2f(v[5]) * w1.y +
                       bf2f(v[6]) * w1.z + bf2f(v[7]) * w1.w;
#pragma unroll
            for (int off = 1; off < 16; off <<= 1) pp += __shfl_xor(pp, off, 16);
            if (l == 0 && gr < NN) {
                float h2 = pp + b2v;
                z[gr] = h2;
                s += h2;
                ss += h2 * h2;
            }
        }
        s += __shfl_xor(s, 16); s += __shfl_xor(s, 32);
        ss += __shfl_xor(ss, 16); ss += __shfl_xor(ss, 32);
        if ((t & 63) == 0) { redS[wave * 2] = s; redS[wave * 2 + 1] = ss; }
        __syncthreads();
        if (t == 0) {
            float S = 0.f, SS = 0.f;
#pragma unroll
            for (int w = 0; w < 8; ++w) { S += redS[w * 2]; SS += redS[w * 2 + 1]; }
            int rp = (blockIdx.x & 7) * 2;
            unsafeAtomicAdd(&s2rep[rp], S);
            unsafeAtomicAdd(&s2rep[rp + 1], SS);
        }
        return;
    } else {
        // ---- gemm2 ----
#pragma unroll
        for (int rt = 0; rt < 2; ++rt)
#pragma unroll
            for (int ct = 0; ct < 4; ++ct) acc[rt][ct] = (f32x4)0.f;
#pragma unroll
        for (int kk = 0; kk < 4; ++kk) {
            short8 b[4], a[2];
#pragma unroll
            for (int ct = 0; ct < 4; ++ct)
                b[ct] = *(const short8*)&Wsb[swz(CB + ct * 16 + r16, kk * 4 + q)];
#pragma unroll
            for (int rt = 0; rt < 2; ++rt)
                a[rt] = *(const short8*)&Asb[swz(RA + rt * 16 + r16, kk * 4 + q)];
#pragma unroll
            for (int rt = 0; rt < 2; ++rt)
#pragma unroll
                for (int ct = 0; ct < 4; ++ct)
                    acc[rt][ct] = __builtin_amdgcn_mfma_f32_16x16x32_bf16(a[rt], b[ct], acc[rt][ct], 0, 0, 0);
        }
        __syncthreads();  // gemm2 LDS reads done

        float bbv[4];
#pragma unroll
        for (int ct = 0; ct < 4; ++ct) bbv[ct] = bb[CB + ct * 16 + r16];
        float s[4] = {0.f, 0.f, 0.f, 0.f}, ss[4] = {0.f, 0.f, 0.f, 0.f};
#pragma unroll
        for (int rt = 0; rt < 2; ++rt)
#pragma unroll
            for (int ct = 0; ct < 4; ++ct)
#pragma unroll
                for (int rg = 0; rg < 4; ++rg) {
                    int lr = RA + rt * 16 + q * 4 + rg;
                    int gr = row0 + lr;
                    float hv = acc[rt][ct][rg] + bbv[ct];
                    if (gr < NN) { s[ct] += hv; ss[ct] += hv * hv; }
                    Asb[swze(lr, CB + ct * 16 + r16)] = f2bf(hv);
                }
#pragma unroll
        for (int ct = 0; ct < 4; ++ct) {
            s[ct] += __shfl_xor(s[ct], 16);
            s[ct] += __shfl_xor(s[ct], 32);
            ss[ct] += __shfl_xor(ss[ct], 16);
            ss[ct] += __shfl_xor(ss[ct], 32);
        }
        if (lane < 16) {
#pragma unroll
            for (int ct = 0; ct < 4; ++ct) {
                int col = CB + ct * 16 + r16;
                redS[rh * 256 + col] = s[ct];
                redS[rh * 256 + 128 + col] = ss[ct];
            }
        }
        __syncthreads();
        if (t < 256) {
            float v = redS[t] + redS[256 + t] + redS[512 + t] + redS[768 + t];
            unsafeAtomicAdd(&statsRep[(blockIdx.x & 7) * 256 + t], v);
        }
        // coalesced bf16 store of h tile
#pragma unroll
        for (int i = 0; i < 4; ++i) {
            int f = i * 512 + t;
            int r = f >> 4, c8 = f & 15;
            int gr = row0 + r;
            if (gr < NN)
                *(short8*)(hout + (size_t)gr * 128 + c8 * 8) = *(const short8*)&Asb[swz(r, c8)];
        }
    }
}

__device__ __forceinline__ int lbound(const int* __restrict__ b, int val) {
    int lo = 0, hi = NN;
    while (lo < hi) {
        int m = (lo + hi) >> 1;
        if (b[m] < val) lo = m + 1; else hi = m;
    }
    return lo;
}

// fused BN(1) + segment softmax(temp 5): one block per graph (batch sorted)
__global__ void k_softmax(const float* __restrict__ zr, const float* __restrict__ s2rep,
                          const float* __restrict__ g2, const float* __restrict__ be2,
                          const int* __restrict__ batch, float* __restrict__ out) {
    __shared__ float rb[4];
    const int g = blockIdx.x, t = threadIdx.x;
    const int lo = lbound(batch, g), hi = lbound(batch, g + 1);
    float s = 0.f, ssq = 0.f;
#pragma unroll
    for (int i = 0; i < 8; ++i) { s += s2rep[i * 2]; ssq += s2rep[i * 2 + 1]; }
    const float mu = s / (float)NN;
    const float var = ssq / (float)NN - mu * mu;
    const float sc = g2[0] / sqrtf(var + BN_EPS) * 0.2f;
    const float sh = (be2[0] - mu * g2[0] / sqrtf(var + BN_EPS)) * 0.2f;

    float m = -INFINITY;
    for (int i = lo + t; i < hi; i += 256) m = fmaxf(m, fmaf(zr[i], sc, sh));
#pragma unroll
    for (int off = 1; off < 64; off <<= 1) m = fmaxf(m, __shfl_xor(m, off, 64));
    if ((t & 63) == 0) rb[t >> 6] = m;
    __syncthreads();
    float gmax = fmaxf(fmaxf(rb[0], rb[1]), fmaxf(rb[2], rb[3]));
    __syncthreads();

    float sum = 0.f;
    for (int i = lo + t; i < hi; i += 256) {
        float e = expf(fmaf(zr[i], sc, sh) - gmax);
        out[i] = e;
        sum += e;
    }
#pragma unroll
    for (int off = 1; off < 64; off <<= 1) sum += __shfl_xor(sum, off, 64);
    if ((t & 63) == 0) rb[t >> 6] = sum;
    __syncthreads();
    float S = rb[0] + rb[1] + rb[2] + rb[3];
    float inv = 1.0f / (S + 1e-16f);
    for (int i = lo + t; i < hi; i += 256) out[i] *= inv;
}

extern "C" void kernel_launch(void* const* d_in, const int* in_sizes, int n_in,
                              void* d_out, int out_size, void* d_ws, size_t ws_size,
                              hipStream_t stream) {
    const float* x   = (const float*)d_in[0];
    const int* ei    = (const int*)d_in[1];
    const int* batch = (const int*)d_in[2];
    const float *W0a = (const float*)d_in[3],  *b0a = (const float*)d_in[4];
    const float *W0b = (const float*)d_in[5],  *b0b = (const float*)d_in[6];
    const float *g0  = (const float*)d_in[7],  *be0 = (const float*)d_in[8];
    const float *W1a = (const float*)d_in[9],  *b1a = (const float*)d_in[10];
    const float *W1b = (const float*)d_in[11], *b1b = (const float*)d_in[12];
    const float *g1  = (const float*)d_in[13], *be1 = (const float*)d_in[14];
    const float *W2a = (const float*)d_in[15], *b2a = (const float*)d_in[16];
    const float *W2b = (const float*)d_in[17], *b2b = (const float*)d_in[18];
    const float *g2  = (const float*)d_in[19], *be2 = (const float*)d_in[20];
    float* out = (float*)d_out;

    char* wsb = (char*)d_ws;
    short* Abf = (short*)wsb;
    short* Bbf = (short*)(wsb + 25600000);
    float* Zb  = (float*)(wsb + 51200000);
    float* SMf = (float*)(wsb + 51600000);
    float* S0r = SMf;               // 8 x 256
    float* S1r = SMf + 2048;        // 8 x 256
    float* S2r = SMf + 4096;        // 8 x 2
    int* offs  = (int*)(wsb + 51620000);
    int* bsums = (int*)(wsb + 52020004);
    int* csr   = (int*)(wsb + 52020516);
    short* Wt  = (short*)(wsb + 54580544);
    short* Xbf = (short*)(wsb + 54744384);
    // deg/pos alias Abf during CSR build
    int* deg = (int*)wsb;
    int* pos = (int*)(wsb + 400000);

    const int gE    = (EE + 255) / 256;     // 2500
    const int gGmlp = (NN + 127) / 128;     // 782

    k_setup<<<6250, 256, 0, stream>>>(x, W0a, W0b, W1a, W1b, W2a, Wt, Xbf, deg, SMf);

    // ---- CSR build (reused all 3 layers) ----
    k_hist<<<gE, 256, 0, stream>>>(ei, deg);
    k_scan1<<<NBLK, 1024, 0, stream>>>(deg, offs, bsums);
    k_scan3<<<NBLK, 1024, 0, stream>>>(offs, bsums, pos);
    k_fill<<<gE, 256, 0, stream>>>(ei, pos, csr);

    // layer 0: fused gather(Xbf) + MLP -> Abf + stats
    k_gmlp<0><<<gGmlp, 512, 0, stream>>>(Xbf, offs, csr, nullptr, nullptr, nullptr,
                                         Wt, b0a, Wt + 16384, b0b, Abf, S0r,
                                         nullptr, nullptr, nullptr, nullptr);
    // layer 1: fused gather(Abf, BN0+ReLU) + MLP -> Bbf + stats
    k_gmlp<1><<<gGmlp, 512, 0, stream>>>(Abf, offs, csr, S0r, g0, be0,
                                         Wt + 2 * 16384, b1a, Wt + 3 * 16384, b1b, Bbf, S1r,
                                         nullptr, nullptr, nullptr, nullptr);
    // layer 2: fused gather(Bbf, BN1+ReLU) + gemm1 + final dot -> Zb + s2
    k_gmlp<2><<<gGmlp, 512, 0, stream>>>(Bbf, offs, csr, S1r, g1, be1,
                                         Wt + 4 * 16384, b2a, nullptr, nullptr,
                                         nullptr, nullptr, W2b, b2b, Zb, S2r);

    // fused BN(1) + segment softmax (temperature 5)
    k_softmax<<<GG, 256, 0, stream>>>(Zb, S2r, g2, be2, batch, out);
}